// Round 1
// baseline (336.097 us; speedup 1.0000x reference)
//
#include <hip/hip_runtime.h>
#include <hip/hip_bf16.h>

typedef __attribute__((ext_vector_type(8))) short short8v;
typedef __attribute__((ext_vector_type(4))) short short4v;
typedef __attribute__((ext_vector_type(4))) float floatx4;

__device__ __forceinline__ unsigned int pkbf(float a, float b) {
  __hip_bfloat162 h = __float22bfloat162_rn(make_float2(a, b));
  union { __hip_bfloat162 h; unsigned int u; } c; c.h = h;
  return c.u;
}

// out[b*128+o] = bias[o]
__global__ void bias_init(const float* __restrict__ bias, float* __restrict__ out) {
  int idx = blockIdx.x * 256 + threadIdx.x;   // 32768 total
  out[idx] = bias[idx & 127];
}

// GEMM: out[256,128] += F[256, Kchunk] @ W[Kchunk, 128]
// F[b, gk] = a[b,i] * p[b,j] * d[b,k],  gk = (i*64+j)*64+k
// block c owns gk in [c*1024, (c+1)*1024): i = c>>2 fixed, j in [ (c&3)*16, +16 ), k full [0,64)
__global__ __launch_bounds__(512, 2)
void tfn_gemm(const float* __restrict__ X, const float* __restrict__ P,
              const float* __restrict__ Dyn, const float* __restrict__ W,
              float* __restrict__ out) {
  constexpr int WT_STRIDE = 36;               // 32 bf16 + 4 pad -> 72B rows (8B aligned)
  __shared__ short Wt[2][128][WT_STRIDE];     // B-tile, transposed [n][k], bf16, double buffered
  __shared__ float p_lds[256 * 17];           // p[b][jj], stride 17 -> conflict-free

  const int tid = threadIdx.x;
  const int wv = tid >> 6, lane = tid & 63;
  const int q = lane >> 4, l16 = lane & 15;
  const int r = wv & 3;                       // row group: rows [64r, 64r+64)
  const int cg = wv >> 2;                     // col group: cols [64cg, 64cg+64)

  const int c = blockIdx.x;
  const int i = c >> 2;
  const int j0 = (c & 3) << 4;
  const long gk0 = (long)c << 10;

  // ---- stage p (16 j-values for all 256 batches) into LDS ----
  for (int idx = tid; idx < 256 * 16; idx += 512) {
    int bb = idx >> 4, jj = idx & 15;
    int j = j0 + jj;
    p_lds[bb * 17 + jj] = (j < 63) ? P[bb * 63 + j] : 1.0f;
  }

  // ---- per-lane register cache: e[b,k] = a[b]*d[b,k] for this lane's rows/k-slots ----
  float e[4][2][8];
  #pragma unroll
  for (int rt = 0; rt < 4; ++rt) {
    int brow = (r << 6) + (rt << 4) + l16;
    float av = (i < 63) ? X[brow * 63 + i] : 1.0f;
    #pragma unroll
    for (int h = 0; h < 2; ++h) {
      int kb = (h << 5) + (q << 3);
      #pragma unroll
      for (int t = 0; t < 8; ++t) {
        int k = kb + t;
        float dv = (k < 63) ? Dyn[brow * 63 + k] : 1.0f;
        e[rt][h][t] = av * dv;
      }
    }
  }

  floatx4 acc[4][4];
  #pragma unroll
  for (int a = 0; a < 4; ++a)
    #pragma unroll
    for (int b = 0; b < 4; ++b) acc[a][b] = (floatx4)0.0f;

  // staging: thread -> (n = tid&127, k-run of 8 starting at (tid>>7)*8)
  const int sn = tid & 127;
  const int skk = (tid >> 7) << 3;

  float w[8];
  {   // prologue: tile 0
    const float* wp = W + (gk0 + skk) * 128 + sn;
    #pragma unroll
    for (int u = 0; u < 8; ++u) w[u] = wp[u * 128];
    short* dst = &Wt[0][sn][skk];
    unsigned int* d32 = (unsigned int*)dst;
    d32[0] = pkbf(w[0], w[1]); d32[1] = pkbf(w[2], w[3]);
    d32[2] = pkbf(w[4], w[5]); d32[3] = pkbf(w[6], w[7]);
  }
  __syncthreads();

  for (int s = 0; s < 32; ++s) {
    const int cur = s & 1;

    // issue next tile's global loads early (latency overlap with compute below)
    if (s < 31) {
      const float* wp = W + (gk0 + (long)(s + 1) * 32 + skk) * 128 + sn;
      #pragma unroll
      for (int u = 0; u < 8; ++u) w[u] = wp[u * 128];
    }

    // B fragments: 8 consecutive k at fixed n, from transposed LDS tile
    union { short8v v; short4v h[2]; } fb[4];
    #pragma unroll
    for (int nt = 0; nt < 4; ++nt) {
      const short* src = &Wt[cur][(cg << 6) + (nt << 4) + l16][q << 3];
      fb[nt].h[0] = *(const short4v*)src;
      fb[nt].h[1] = *(const short4v*)(src + 4);
    }

    // A fragments: F = p * e, computed in registers, packed to bf16
    const int jj = s >> 1, h = s & 1;
    union { short8v v; unsigned int u[4]; } fa[4];
    #pragma unroll
    for (int rt = 0; rt < 4; ++rt) {
      float pb = p_lds[((r << 6) + (rt << 4) + l16) * 17 + jj];
      #pragma unroll
      for (int v2 = 0; v2 < 4; ++v2)
        fa[rt].u[v2] = pkbf(pb * e[rt][h][2 * v2], pb * e[rt][h][2 * v2 + 1]);
    }

    #pragma unroll
    for (int rt = 0; rt < 4; ++rt)
      #pragma unroll
      for (int nt = 0; nt < 4; ++nt)
        acc[rt][nt] = __builtin_amdgcn_mfma_f32_16x16x32_bf16(
            fa[rt].v, fb[nt].v, acc[rt][nt], 0, 0, 0);

    // convert + write next tile into the other buffer
    if (s < 31) {
      short* dst = &Wt[1 - cur][sn][skk];
      unsigned int* d32 = (unsigned int*)dst;
      d32[0] = pkbf(w[0], w[1]); d32[1] = pkbf(w[2], w[3]);
      d32[2] = pkbf(w[4], w[5]); d32[3] = pkbf(w[6], w[7]);
    }
    __syncthreads();
  }

  // epilogue: device-scope atomic accumulate into out (initialized with bias)
  #pragma unroll
  for (int rt = 0; rt < 4; ++rt) {
    #pragma unroll
    for (int nt = 0; nt < 4; ++nt) {
      int col = (cg << 6) + (nt << 4) + l16;
      #pragma unroll
      for (int g = 0; g < 4; ++g) {
        int brow = (r << 6) + (rt << 4) + (q << 2) + g;
        atomicAdd(&out[brow * 128 + col], acc[rt][nt][g]);
      }
    }
  }
}

extern "C" void kernel_launch(void* const* d_in, const int* in_sizes, int n_in,
                              void* d_out, int out_size, void* d_ws, size_t ws_size,
                              hipStream_t stream) {
  const float* x   = (const float*)d_in[0];
  const float* p   = (const float*)d_in[1];
  const float* dyn = (const float*)d_in[2];
  const float* W   = (const float*)d_in[3];
  const float* b   = (const float*)d_in[4];
  float* out = (float*)d_out;

  bias_init<<<128, 256, 0, stream>>>(b, out);
  tfn_gemm<<<256, 512, 0, stream>>>(x, p, dyn, W, out);
}

// Round 2
// 246.619 us; speedup vs baseline: 1.3628x; 1.3628x over previous
//
#include <hip/hip_runtime.h>
#include <hip/hip_bf16.h>

typedef __attribute__((ext_vector_type(8))) short short8v;
typedef __attribute__((ext_vector_type(4))) short short4v;
typedef __attribute__((ext_vector_type(4))) float floatx4;

__device__ __forceinline__ unsigned int pkbf(float a, float b) {
  __hip_bfloat162 h = __float22bfloat162_rn(make_float2(a, b));
  union { __hip_bfloat162 h; unsigned int u; } c; c.h = h;
  return c.u;
}

// out[b*128+o] = bias[o]
__global__ void bias_init(const float* __restrict__ bias, float* __restrict__ out) {
  int idx = blockIdx.x * 256 + threadIdx.x;   // 32768 total
  out[idx] = bias[idx & 127];
}

// GEMM: out[256,128] += F[256, Kchunk] @ W[Kchunk, 128]
// F[b, gk] = a[b,i] * p[b,j] * d[b,k],  gk = (i*64+j)*64+k
// block c owns gk in [c*1024, (c+1)*1024): i = c>>2 fixed, j in [ (c&3)*16, +16 ), k full [0,64)
__global__ __launch_bounds__(512, 2)
void tfn_gemm(const float* __restrict__ X, const float* __restrict__ P,
              const float* __restrict__ Dyn, const float* __restrict__ W,
              float* __restrict__ out) {
  constexpr int WT_STRIDE = 36;               // 32 bf16 + 4 pad -> 72B rows (8B aligned)
  __shared__ short Wt[2][128][WT_STRIDE];     // B-tile, transposed [n][k], bf16, double buffered
  __shared__ float p_lds[256 * 17];           // p[b][jj], stride 17 -> conflict-free

  const int tid = threadIdx.x;
  const int wv = tid >> 6, lane = tid & 63;
  const int q = lane >> 4, l16 = lane & 15;
  const int r = wv & 3;                       // row group: rows [64r, 64r+64)
  const int cg = wv >> 2;                     // col group: cols [64cg, 64cg+64)

  const int c = blockIdx.x;
  const int i = c >> 2;
  const int j0 = (c & 3) << 4;
  const long gk0 = (long)c << 10;

  // ---- stage p (16 j-values for all 256 batches) into LDS ----
  for (int idx = tid; idx < 256 * 16; idx += 512) {
    int bb = idx >> 4, jj = idx & 15;
    int j = j0 + jj;
    p_lds[bb * 17 + jj] = (j < 63) ? P[bb * 63 + j] : 1.0f;
  }

  // ---- per-lane register cache: e[b,k] = a[b]*d[b,k] (STATIC indexing only!) ----
  float e[4][2][8];
  #pragma unroll
  for (int rt = 0; rt < 4; ++rt) {
    int brow = (r << 6) + (rt << 4) + l16;
    float av = (i < 63) ? X[brow * 63 + i] : 1.0f;
    #pragma unroll
    for (int h = 0; h < 2; ++h) {
      int kb = (h << 5) + (q << 3);
      #pragma unroll
      for (int t = 0; t < 8; ++t) {
        int k = kb + t;
        float dv = (k < 63) ? Dyn[brow * 63 + k] : 1.0f;
        e[rt][h][t] = av * dv;
      }
    }
  }

  floatx4 acc[4][4];
  #pragma unroll
  for (int a = 0; a < 4; ++a)
    #pragma unroll
    for (int b = 0; b < 4; ++b) acc[a][b] = (floatx4)0.0f;

  // staging: thread -> (n = tid&127, k-run of 8 starting at (tid>>7)*8)
  const int sn = tid & 127;
  const int skk = (tid >> 7) << 3;

  float w[8];
  {   // prologue: tile 0
    const float* wp = W + (gk0 + skk) * 128 + sn;
    #pragma unroll
    for (int u = 0; u < 8; ++u) w[u] = wp[u * 128];
    short* dst = &Wt[0][sn][skk];
    unsigned int* d32 = (unsigned int*)dst;
    d32[0] = pkbf(w[0], w[1]); d32[1] = pkbf(w[2], w[3]);
    d32[2] = pkbf(w[4], w[5]); d32[3] = pkbf(w[6], w[7]);
  }
  __syncthreads();

  // K-loop: outer jj (dynamic, only indexes LDS), inner h fully unrolled so
  // every e[][][] index is a compile-time constant -> e stays in VGPRs.
  for (int jj = 0; jj < 16; ++jj) {
    // p values for this jj (used by both halves)
    float pb[4];
    #pragma unroll
    for (int rt = 0; rt < 4; ++rt)
      pb[rt] = p_lds[((r << 6) + (rt << 4) + l16) * 17 + jj];

    #pragma unroll
    for (int h = 0; h < 2; ++h) {
      const int s = (jj << 1) | h;
      const int cur = h;            // tile s lives in buffer s&1

      // issue next tile's global loads early (latency overlap with compute below)
      if (s < 31) {
        const float* wp = W + (gk0 + (long)(s + 1) * 32 + skk) * 128 + sn;
        #pragma unroll
        for (int u = 0; u < 8; ++u) w[u] = wp[u * 128];
      }

      // B fragments: 8 consecutive k at fixed n, from transposed LDS tile
      union { short8v v; short4v hv[2]; } fb[4];
      #pragma unroll
      for (int nt = 0; nt < 4; ++nt) {
        const short* src = &Wt[cur][(cg << 6) + (nt << 4) + l16][q << 3];
        fb[nt].hv[0] = *(const short4v*)src;
        fb[nt].hv[1] = *(const short4v*)(src + 4);
      }

      // A fragments: F = p * e, computed in registers, packed to bf16
      union { short8v v; unsigned int u[4]; } fa[4];
      #pragma unroll
      for (int rt = 0; rt < 4; ++rt) {
        #pragma unroll
        for (int v2 = 0; v2 < 4; ++v2)
          fa[rt].u[v2] = pkbf(pb[rt] * e[rt][h][2 * v2], pb[rt] * e[rt][h][2 * v2 + 1]);
      }

      #pragma unroll
      for (int rt = 0; rt < 4; ++rt)
        #pragma unroll
        for (int nt = 0; nt < 4; ++nt)
          acc[rt][nt] = __builtin_amdgcn_mfma_f32_16x16x32_bf16(
              fa[rt].v, fb[nt].v, acc[rt][nt], 0, 0, 0);

      // convert + write next tile into the other buffer
      if (s < 31) {
        short* dst = &Wt[1 - cur][sn][skk];
        unsigned int* d32 = (unsigned int*)dst;
        d32[0] = pkbf(w[0], w[1]); d32[1] = pkbf(w[2], w[3]);
        d32[2] = pkbf(w[4], w[5]); d32[3] = pkbf(w[6], w[7]);
      }
      __syncthreads();
    }
  }

  // epilogue: device-scope atomic accumulate into out (initialized with bias)
  #pragma unroll
  for (int rt = 0; rt < 4; ++rt) {
    #pragma unroll
    for (int nt = 0; nt < 4; ++nt) {
      int col = (cg << 6) + (nt << 4) + l16;
      #pragma unroll
      for (int g = 0; g < 4; ++g) {
        int brow = (r << 6) + (rt << 4) + (q << 2) + g;
        atomicAdd(&out[brow * 128 + col], acc[rt][nt][g]);
      }
    }
  }
}

extern "C" void kernel_launch(void* const* d_in, const int* in_sizes, int n_in,
                              void* d_out, int out_size, void* d_ws, size_t ws_size,
                              hipStream_t stream) {
  const float* x   = (const float*)d_in[0];
  const float* p   = (const float*)d_in[1];
  const float* dyn = (const float*)d_in[2];
  const float* W   = (const float*)d_in[3];
  const float* b   = (const float*)d_in[4];
  float* out = (float*)d_out;

  bias_init<<<128, 256, 0, stream>>>(b, out);
  tfn_gemm<<<256, 512, 0, stream>>>(x, p, dyn, W, out);
}

// Round 3
// 240.577 us; speedup vs baseline: 1.3970x; 1.0251x over previous
//
#include <hip/hip_runtime.h>
#include <hip/hip_bf16.h>

typedef __attribute__((ext_vector_type(8))) short short8v;
typedef __attribute__((ext_vector_type(4))) float floatx4;

__device__ __forceinline__ unsigned int pkbf(float a, float b) {
  __hip_bfloat162 h = __float22bfloat162_rn(make_float2(a, b));
  union { __hip_bfloat162 h; unsigned int u; } c; c.h = h;
  return c.u;
}

// out[b*128+o] = bias[o]   (atomic-fallback path only)
__global__ void bias_init(const float* __restrict__ bias, float* __restrict__ out) {
  int idx = blockIdx.x * 256 + threadIdx.x;   // 32768 total
  out[idx] = bias[idx & 127];
}

// Sum 256 per-block partials + bias -> out.  grid 256 x 128.
__global__ __launch_bounds__(128)
void reduce_k(const float* __restrict__ part, const float* __restrict__ bias,
              float* __restrict__ out) {
  int o = blockIdx.x * 128 + threadIdx.x;     // 0..32767
  const float* p = part + o;
  float s0 = 0.f, s1 = 0.f, s2 = 0.f, s3 = 0.f;
  #pragma unroll 8
  for (int c = 0; c < 256; c += 4) {
    s0 += p[(long)c * 32768];
    s1 += p[(long)(c + 1) * 32768];
    s2 += p[(long)(c + 2) * 32768];
    s3 += p[(long)(c + 3) * 32768];
  }
  out[o] = s0 + s1 + s2 + s3 + bias[o & 127];
}

// GEMM: partial_c[256,128] = F[256, Kchunk_c] @ W[Kchunk_c, 128]
// F[b, gk] = a[b,i]*p[b,j]*d[b,k],  gk = (i*64+j)*64+k
// block c: i = c>>2 fixed, j in [(c&3)*16, +16), k full [0,64).
// Barrier-free K-loop: W fragments loaded straight from global (fp32) and
// converted in-register; only one __syncthreads (after p staging).
__global__ __launch_bounds__(512, 2)
void tfn_gemm(const float* __restrict__ X, const float* __restrict__ P,
              const float* __restrict__ Dyn, const float* __restrict__ W,
              float* __restrict__ part, float* __restrict__ out, int use_ws) {
  __shared__ float p_lds[16][256];            // p[jj][brow]

  const int tid = threadIdx.x;
  const int wv = tid >> 6, lane = tid & 63;
  const int q = lane >> 4, l16 = lane & 15;
  const int r = wv & 3;                       // row group: rows [64r, 64r+64)
  const int cg = wv >> 2;                     // col group: cols [64cg, 64cg+64)

  const int c = blockIdx.x;
  const int i = c >> 2;
  const int j0 = (c & 3) << 4;
  const long gk0 = (long)c << 10;

  // ---- stage p (16 j-values for all 256 batches) into LDS, transposed ----
  for (int idx = tid; idx < 256 * 16; idx += 512) {
    int bb = idx >> 4, jj = idx & 15;
    int j = j0 + jj;
    p_lds[jj][bb] = (j < 63) ? P[bb * 63 + j] : 1.0f;
  }

  // ---- per-lane register cache: e[rt][h][t] = a * d  (static indices only) ----
  float e[4][2][8];
  #pragma unroll
  for (int rt = 0; rt < 4; ++rt) {
    int brow = (r << 6) + (rt << 4) + l16;
    float av = (i < 63) ? X[brow * 63 + i] : 1.0f;
    #pragma unroll
    for (int h = 0; h < 2; ++h) {
      int kb = (h << 5) + (q << 3);
      #pragma unroll
      for (int t = 0; t < 8; ++t) {
        int k = kb + t;
        float dv = (k < 63) ? Dyn[brow * 63 + k] : 1.0f;
        e[rt][h][t] = av * dv;
      }
    }
  }

  floatx4 acc[4][4];
  #pragma unroll
  for (int a = 0; a < 4; ++a)
    #pragma unroll
    for (int b = 0; b < 4; ++b) acc[a][b] = (floatx4)0.0f;

  __syncthreads();   // p_lds ready; no barriers after this point

  // fragment base: element (s, t, nt) at wstep[s*4096 + t*128 + nt*16]
  // = W[(gk0 + s*32 + q*8 + t)*128 + cg*64 + nt*16 + l16]
  const float* wstep = W + (gk0 + (q << 3)) * 128 + (cg << 6) + l16;

  float wA[4][8], wB[4][8];   // [nt][t] fp32 fragments, double-buffered in regs

  #pragma unroll
  for (int nt = 0; nt < 4; ++nt)
    #pragma unroll
    for (int t = 0; t < 8; ++t)
      wA[nt][t] = wstep[t * 128 + nt * 16];          // s = 0

  for (int jj = 0; jj < 16; ++jj) {
    float pb[4];
    #pragma unroll
    for (int rt = 0; rt < 4; ++rt)
      pb[rt] = p_lds[jj][(r << 6) + (rt << 4) + l16];

    // ---- h = 0 : compute with wA, prefetch wB (s = 2jj+1) ----
    {
      const float* wp = wstep + ((long)(2 * jj + 1) << 12);
      #pragma unroll
      for (int nt = 0; nt < 4; ++nt)
        #pragma unroll
        for (int t = 0; t < 8; ++t)
          wB[nt][t] = wp[t * 128 + nt * 16];

      union { short8v v; unsigned int u[4]; } fb[4], fa[4];
      #pragma unroll
      for (int nt = 0; nt < 4; ++nt)
        #pragma unroll
        for (int v2 = 0; v2 < 4; ++v2)
          fb[nt].u[v2] = pkbf(wA[nt][2 * v2], wA[nt][2 * v2 + 1]);
      #pragma unroll
      for (int rt = 0; rt < 4; ++rt)
        #pragma unroll
        for (int v2 = 0; v2 < 4; ++v2)
          fa[rt].u[v2] = pkbf(pb[rt] * e[rt][0][2 * v2], pb[rt] * e[rt][0][2 * v2 + 1]);
      #pragma unroll
      for (int rt = 0; rt < 4; ++rt)
        #pragma unroll
        for (int nt = 0; nt < 4; ++nt)
          acc[rt][nt] = __builtin_amdgcn_mfma_f32_16x16x32_bf16(
              fa[rt].v, fb[nt].v, acc[rt][nt], 0, 0, 0);
    }

    // ---- h = 1 : compute with wB, prefetch wA (s = 2jj+2) ----
    {
      if (jj < 15) {
        const float* wp = wstep + ((long)(2 * jj + 2) << 12);
        #pragma unroll
        for (int nt = 0; nt < 4; ++nt)
          #pragma unroll
          for (int t = 0; t < 8; ++t)
            wA[nt][t] = wp[t * 128 + nt * 16];
      }

      union { short8v v; unsigned int u[4]; } fb[4], fa[4];
      #pragma unroll
      for (int nt = 0; nt < 4; ++nt)
        #pragma unroll
        for (int v2 = 0; v2 < 4; ++v2)
          fb[nt].u[v2] = pkbf(wB[nt][2 * v2], wB[nt][2 * v2 + 1]);
      #pragma unroll
      for (int rt = 0; rt < 4; ++rt)
        #pragma unroll
        for (int v2 = 0; v2 < 4; ++v2)
          fa[rt].u[v2] = pkbf(pb[rt] * e[rt][1][2 * v2], pb[rt] * e[rt][1][2 * v2 + 1]);
      #pragma unroll
      for (int rt = 0; rt < 4; ++rt)
        #pragma unroll
        for (int nt = 0; nt < 4; ++nt)
          acc[rt][nt] = __builtin_amdgcn_mfma_f32_16x16x32_bf16(
              fa[rt].v, fb[nt].v, acc[rt][nt], 0, 0, 0);
    }
  }

  // ---- epilogue ----
  if (use_ws) {
    float* pt = part + ((long)c << 15);
    #pragma unroll
    for (int rt = 0; rt < 4; ++rt)
      #pragma unroll
      for (int nt = 0; nt < 4; ++nt) {
        int col = (cg << 6) + (nt << 4) + l16;
        #pragma unroll
        for (int g = 0; g < 4; ++g) {
          int brow = (r << 6) + (rt << 4) + (q << 2) + g;
          pt[brow * 128 + col] = acc[rt][nt][g];
        }
      }
  } else {
    #pragma unroll
    for (int rt = 0; rt < 4; ++rt)
      #pragma unroll
      for (int nt = 0; nt < 4; ++nt) {
        int col = (cg << 6) + (nt << 4) + l16;
        #pragma unroll
        for (int g = 0; g < 4; ++g) {
          int brow = (r << 6) + (rt << 4) + (q << 2) + g;
          atomicAdd(&out[brow * 128 + col], acc[rt][nt][g]);
        }
      }
  }
}

extern "C" void kernel_launch(void* const* d_in, const int* in_sizes, int n_in,
                              void* d_out, int out_size, void* d_ws, size_t ws_size,
                              hipStream_t stream) {
  const float* x   = (const float*)d_in[0];
  const float* p   = (const float*)d_in[1];
  const float* dyn = (const float*)d_in[2];
  const float* W   = (const float*)d_in[3];
  const float* b   = (const float*)d_in[4];
  float* out = (float*)d_out;

  const size_t need = (size_t)256 * 32768 * sizeof(float);   // 33.5 MB
  if (d_ws != nullptr && ws_size >= need) {
    float* part = (float*)d_ws;
    tfn_gemm<<<256, 512, 0, stream>>>(x, p, dyn, W, part, out, 1);
    reduce_k<<<256, 128, 0, stream>>>(part, b, out);
  } else {
    bias_init<<<128, 256, 0, stream>>>(b, out);
    tfn_gemm<<<256, 512, 0, stream>>>(x, p, dyn, W, nullptr, out, 0);
  }
}